// Round 19
// baseline (208.123 us; speedup 1.0000x reference)
//
#include <hip/hip_runtime.h>

#define D_MODEL 1024
#define QLEN 1024

typedef __bf16 bf16x8 __attribute__((ext_vector_type(8)));
typedef __bf16 bf16x4 __attribute__((ext_vector_type(4)));
typedef float f32x4 __attribute__((ext_vector_type(4)));

__device__ __forceinline__ void gload16(const void* g, void* l) {
    __builtin_amdgcn_global_load_lds(
        (const __attribute__((address_space(1))) void*)g,
        (__attribute__((address_space(3))) void*)l, 16, 0, 0);
}

// ============ GEMM core v2: BK=32, 4-buffer ring, prefetch dist 3, 1 barrier/step ============
// 8 waves / 512 threads, C tile 128x128. LDS: A 4x[128][32] + B 4x[128][32] = 64KB.
// Swizzle: chunk' = chunk ^ ((row>>1)&3) -> 2-way bank aliasing (free).
__device__ __forceinline__ void gemm_core8p3(
    __bf16* __restrict__ smA, __bf16* __restrict__ smB,
    const __bf16* __restrict__ A, const __bf16* __restrict__ Bt,
    float* __restrict__ C, __bf16* __restrict__ Cb,
    const float* __restrict__ U, const float* __restrict__ Ut,
    const float* __restrict__ bias,
    int K, int lda, int ldb, int ldC, int ldU, int relu, int m0, int n0)
{
    const int t = threadIdx.x;
    const int lane = t & 63, w = t >> 6;
    const int l15 = lane & 15, lg = lane >> 4;          // lg in 0..3 = k-chunk
    const int wm = w >> 2, wn = w & 3;
    const int NK = K >> 5;                               // BK = 32
    const int ABUF = 4096;                               // elems per 128x32 buffer

    const int srow = w * 16 + (lane >> 2);               // staging row this lane covers
    const int scol = (lane & 3) ^ ((srow >> 1) & 3);     // pre-swizzled source chunk

    #define STAGE3(buf, kt)                                                     \
    {                                                                           \
        int k0s = (kt) * 32;                                                    \
        gload16(&A[(long long)(m0 + srow) * lda + k0s + scol * 8],              \
                &smA[(buf) * ABUF + (w * 16) * 32]);                            \
        gload16(&Bt[(long long)(n0 + srow) * ldb + k0s + scol * 8],             \
                &smB[(buf) * ABUF + (w * 16) * 32]);                            \
    }

    f32x4 acc[4][2] = {};
    STAGE3(0, 0); STAGE3(1, 1); STAGE3(2, 2);            // 6 loads in flight / wave

    for (int kt = 0; kt < NK; ++kt) {
        const int cb = kt & 3;
        // complete tile kt (leave deeper prefetches in flight); drain own ds_reads
        if (kt + 2 < NK)      asm volatile("s_waitcnt vmcnt(4) lgkmcnt(0)" ::: "memory");
        else if (kt + 1 < NK) asm volatile("s_waitcnt vmcnt(2) lgkmcnt(0)" ::: "memory");
        else                  asm volatile("s_waitcnt vmcnt(0) lgkmcnt(0)" ::: "memory");
        __builtin_amdgcn_sched_barrier(0);
        __builtin_amdgcn_s_barrier();                    // single barrier per K-step
        // stage tile kt+3 into buf (kt+3)&3 == (kt-1)&3: read finished iter kt-1,
        // all waves drained lgkm before THIS barrier -> safe. Distinct from cb and
        // both in-flight buffers (4 distinct residues mod 4).
        if (kt + 3 < NK) STAGE3((kt + 3) & 3, kt + 3);

        bf16x8 bfr[2];
        #pragma unroll
        for (int nt = 0; nt < 2; ++nt) {
            int nr = wn * 32 + nt * 16 + l15;
            bfr[nt] = *(const bf16x8*)&smB[cb * ABUF + nr * 32 + ((lg ^ ((nr >> 1) & 3)) * 8)];
        }
        __builtin_amdgcn_s_setprio(1);
        #pragma unroll
        for (int mt = 0; mt < 4; ++mt) {
            int mr = wm * 64 + mt * 16 + l15;
            bf16x8 afr = *(const bf16x8*)&smA[cb * ABUF + mr * 32 + ((lg ^ ((mr >> 1) & 3)) * 8)];
            acc[mt][0] = __builtin_amdgcn_mfma_f32_16x16x32_bf16(afr, bfr[0], acc[mt][0], 0, 0, 0);
            acc[mt][1] = __builtin_amdgcn_mfma_f32_16x16x32_bf16(afr, bfr[1], acc[mt][1], 0, 0, 0);
        }
        __builtin_amdgcn_s_setprio(0);
    }
    #undef STAGE3

    // ---- Ut epilogue: stage u[n0..+128][m0..+128] fp32 via LDS (2 halves) ----
    if (Ut) {
        float* uf = (float*)smA;           // 64x132 fp32 = 33.8KB (< 64KB total, post-loop)
        #pragma unroll
        for (int hh = 0; hh < 2; ++hh) {
            __syncthreads();
            int r = t >> 3, c0 = (t & 7) * 16;
            const float* src = &Ut[(long long)(n0 + hh * 64 + r) * ldU + m0 + c0];
            #pragma unroll
            for (int k = 0; k < 4; ++k)
                *(float4*)&uf[r * 132 + c0 + k * 4] = *(const float4*)&src[k * 4];
            __syncthreads();
            if ((wn >> 1) == hh) {
                #pragma unroll
                for (int nt = 0; nt < 2; ++nt) {
                    int rr = wn * 32 + nt * 16 + l15 - hh * 64;
                    #pragma unroll
                    for (int mt = 0; mt < 4; ++mt) {
                        #pragma unroll
                        for (int rg = 0; rg < 4; ++rg) {
                            int m = wm * 64 + mt * 16 + lg * 4 + rg;
                            acc[mt][nt][rg] += uf[rr * 132 + m];
                        }
                    }
                }
            }
        }
    }

    #pragma unroll
    for (int mt = 0; mt < 4; ++mt) {
        #pragma unroll
        for (int nt = 0; nt < 2; ++nt) {
            #pragma unroll
            for (int rg = 0; rg < 4; ++rg) {
                int m = m0 + wm * 64 + mt * 16 + lg * 4 + rg;
                int n = n0 + wn * 32 + nt * 16 + l15;
                float v = acc[mt][nt][rg];
                if (U)    v += U[(long long)m * ldU + n];
                if (bias) v += bias[n];
                if (relu) v = fmaxf(v, 0.0f);
                if (Cb) Cb[(long long)m * ldC + n] = (__bf16)v;
                else    C [(long long)m * ldC + n] = v;
            }
        }
    }
}

// ============ GEMM core v1 (2-phase BK=64) — used by the standalone wrappers ============
__device__ __forceinline__ void gemm_core8(
    __bf16* __restrict__ smA, __bf16* __restrict__ smB,
    const __bf16* __restrict__ A, const __bf16* __restrict__ Bt,
    float* __restrict__ C, __bf16* __restrict__ Cb,
    const float* __restrict__ U, const float* __restrict__ Ut,
    const float* __restrict__ bias,
    int K, int lda, int ldb, int ldC, int ldU, int relu, int m0, int n0)
{
    const int t = threadIdx.x;
    const int lane = t & 63, w = t >> 6;
    const int l15 = lane & 15, lg = lane >> 4;
    const int wm = w >> 2, wn = w & 3;
    const int srow = lane >> 3, cpr = lane & 7;
    const int NK = K >> 6;
    const int SZ = 128 * 64;

    #define STAGE(buf, kt)                                                                   \
    {                                                                                        \
        int k0s = (kt) * 64;                                                                 \
        _Pragma("unroll")                                                                    \
        for (int i = 0; i < 2; ++i) {                                                        \
            int r = w * 16 + i * 8 + srow;                                                   \
            int c = cpr ^ (r & 7);                                                           \
            gload16(&A[(long long)(m0 + r) * lda + k0s + c * 8],                             \
                    &smA[(buf) * SZ + (w * 16 + i * 8) * 64]);                               \
            gload16(&Bt[(long long)(n0 + r) * ldb + k0s + c * 8],                            \
                    &smB[(buf) * SZ + (w * 16 + i * 8) * 64]);                               \
        }                                                                                    \
    }

    f32x4 acc[4][2] = {};
    STAGE(0, 0);

    for (int kt = 0; kt < NK; ++kt) {
        const int cb = kt & 1;
        if (kt + 1 < NK) {
            STAGE(cb ^ 1, kt + 1);
            asm volatile("s_waitcnt vmcnt(4)" ::: "memory");
        } else {
            asm volatile("s_waitcnt vmcnt(0)" ::: "memory");
        }
        __builtin_amdgcn_sched_barrier(0);
        __builtin_amdgcn_s_barrier();

        #pragma unroll
        for (int kk = 0; kk < 2; ++kk) {
            bf16x8 bfr[2];
            #pragma unroll
            for (int nt = 0; nt < 2; ++nt) {
                int nr = wn * 32 + nt * 16 + l15;
                bfr[nt] = *(const bf16x8*)&smB[cb * SZ + nr * 64 + (((kk * 4 + lg) ^ (nr & 7)) * 8)];
            }
            #pragma unroll
            for (int mt = 0; mt < 4; ++mt) {
                int mr = wm * 64 + mt * 16 + l15;
                bf16x8 afr = *(const bf16x8*)&smA[cb * SZ + mr * 64 + (((kk * 4 + lg) ^ (mr & 7)) * 8)];
                #pragma unroll
                for (int nt = 0; nt < 2; ++nt)
                    acc[mt][nt] = __builtin_amdgcn_mfma_f32_16x16x32_bf16(afr, bfr[nt], acc[mt][nt], 0, 0, 0);
            }
        }
        asm volatile("s_waitcnt lgkmcnt(0)" ::: "memory");
        __builtin_amdgcn_sched_barrier(0);
        __builtin_amdgcn_s_barrier();
    }
    #undef STAGE

    #pragma unroll
    for (int mt = 0; mt < 4; ++mt) {
        #pragma unroll
        for (int nt = 0; nt < 2; ++nt) {
            #pragma unroll
            for (int rg = 0; rg < 4; ++rg) {
                int m = m0 + wm * 64 + mt * 16 + lg * 4 + rg;
                int n = n0 + wn * 32 + nt * 16 + l15;
                float v = acc[mt][nt][rg];
                if (U)    v += U[(long long)m * ldU + n];
                if (bias) v += bias[n];
                if (relu) v = fmaxf(v, 0.0f);
                if (Cb) Cb[(long long)m * ldC + n] = (__bf16)v;
                else    C [(long long)m * ldC + n] = v;
            }
        }
    }
}

// ============ generic wrapper, KSPLIT-way K-split ============
template<int KSPLIT>
__global__ __launch_bounds__(512) void gemm_bf16_k(
    const __bf16* __restrict__ A, const __bf16* __restrict__ Bt,
    float* __restrict__ C0, float* __restrict__ C1,
    __bf16* __restrict__ Cb,
    const float* __restrict__ U, const float* __restrict__ bias,
    int K, int lda, int ldb, int ldC, int ldU, int relu)
{
    __shared__ __bf16 SM[32768];
    int yb = blockIdx.y;
    int half = 0;
    if (KSPLIT > 1) { half = yb & (KSPLIT - 1); yb /= KSPLIT; }
    const int Keff = K / KSPLIT;
    A  += (long long)half * Keff;
    Bt += (long long)half * Keff;
    float* C = half ? C1 : C0;
    if (half) { bias = nullptr; U = nullptr; }
    gemm_core8(SM, SM + 16384, A, Bt, C, Cb, U, nullptr, bias,
               Keff, lda, ldb, ldC, ldU, relu, yb * 128, blockIdx.x * 128);
}

// ============ fused 3-job GEMM (new 4-buffer core): qkT (512) + wh_v (256) + rkT (72) ============
__global__ __launch_bounds__(512) void gemm_fused3(
    const __bf16* __restrict__ cat_t, const __bf16* __restrict__ Wqkvb,
    __bf16* __restrict__ qkT, const float* __restrict__ u,
    __bf16* __restrict__ wh_v,
    const __bf16* __restrict__ pos_t, const __bf16* __restrict__ Wrb,
    __bf16* __restrict__ rkT)
{
    __shared__ __bf16 SM[32768];
    int bid = blockIdx.x;
    if (bid < 512) {
        int zz = bid >> 8, rem = bid & 255, y = rem >> 4, x = rem & 15;
        gemm_core8p3(SM, SM + 16384,
                     cat_t + (long long)zz * 2097152, Wqkvb,
                     nullptr, qkT + (long long)zz * 4194304,
                     nullptr, u + (long long)zz * 6291456, nullptr,
                     1024, 1024, 1024, 2048, 2048, 0, y * 128, x * 128);
    } else if (bid < 768) {
        int l = bid - 512, zz = l >> 7, rem = l & 127, y = rem >> 4, x = rem & 15;
        gemm_core8p3(SM, SM + 16384,
                     Wqkvb + 2048 * 1024, cat_t + (long long)zz * 2097152,
                     nullptr, wh_v + (long long)zz * 2097152,
                     u + 4194304 + (long long)zz * 6291456, nullptr, nullptr,
                     1024, 1024, 1024, 2048, 2048, 0, y * 128, x * 128);
    } else {
        int l = bid - 768, y = l >> 3, x = l & 7;
        gemm_core8p3(SM, SM + 16384,
                     pos_t + 960 * 1024, Wrb,
                     nullptr, rkT, nullptr, nullptr, nullptr,
                     1024, 1024, 1024, 1024, 0, 0, y * 128, x * 128);
    }
}

// ============ fused prep: weight converts + 3 transposes + pos pad ============
__global__ __launch_bounds__(256) void prep_all(
    const float* __restrict__ Wqkv, __bf16* __restrict__ Wqkvb,
    const float* __restrict__ Wr,   __bf16* __restrict__ Wrb,
    const float* __restrict__ Wo,   __bf16* __restrict__ Wob,
    const float* __restrict__ Wff1, __bf16* __restrict__ Wff1b,
    const float* __restrict__ Wff2, __bf16* __restrict__ Wff2b,
    const float* __restrict__ zh, const float* __restrict__ z, __bf16* __restrict__ cat_t,
    const float* __restrict__ pos, __bf16* __restrict__ pos_t)
{
    __shared__ float ts[32][33];
    int bid = blockIdx.x;
    const int t = threadIdx.x;
    if (bid < 13312) {
        long long i = ((long long)bid * 256 + t) * 4;
        const float* s; __bf16* dd;
        if (i < 3145728)                    { s = Wqkv + i; dd = Wqkvb + i; }
        else if ((i -= 3145728) < 1048576)  { s = Wr + i;   dd = Wrb + i; }
        else if ((i -= 1048576) < 1048576)  { s = Wo + i;   dd = Wob + i; }
        else if ((i -= 1048576) < 4194304)  { s = Wff1 + i; dd = Wff1b + i; }
        else { i -= 4194304;                  s = Wff2 + i; dd = Wff2b + i; }
        float4 v = *(const float4*)s;
        bf16x4 o = { (__bf16)v.x, (__bf16)v.y, (__bf16)v.z, (__bf16)v.w };
        *(bf16x4*)dd = o;
        return;
    }
    bid -= 13312;
    const float* S; __bf16* D; int R, Cc, bx, by;
    if (bid < 2048) {
        int zz = bid >> 10, r2 = bid & 1023;
        S = zh + (long long)zz * 1048576; D = cat_t + (long long)zz * 2097152;
        R = 1024; Cc = 1024; bx = r2 & 31; by = r2 >> 5;
    } else if (bid < 4096) {
        int l = bid - 2048; int zz = l >> 10, r2 = l & 1023;
        S = z + (long long)zz * 1048576; D = cat_t + 1048576 + (long long)zz * 2097152;
        R = 1024; Cc = 1024; bx = r2 & 31; by = r2 >> 5;
    } else if (bid < 6144) {
        int l = bid - 4096;
        S = pos; D = pos_t; R = 1024; Cc = 2048; bx = l & 63; by = l >> 6;
    } else {
        int l = bid - 6144;
        int i = (l * 256 + t) * 4;
        bf16x4 zv = { (__bf16)0.f, (__bf16)0.f, (__bf16)0.f, (__bf16)0.f };
        *(bf16x4*)&pos_t[2048 * 1024 + i] = zv;
        return;
    }
    int r0 = by * 32, c0 = bx * 32;
    int tr = t >> 5, tc = t & 31;
    #pragma unroll
    for (int p = 0; p < 4; ++p)
        ts[tr + p * 8][tc] = S[(long long)(r0 + tr + p * 8) * Cc + c0 + tc];
    __syncthreads();
    #pragma unroll
    for (int p = 0; p < 4; ++p)
        D[(long long)(c0 + tr + p * 8) * R + r0 + tc] = (__bf16)ts[tc][tr + p * 8];
}

// ================= MFMA flash attention: 128-q blocks, 8 waves, shared staging =================
__global__ __launch_bounds__(512) void attn_mfma(
    const __bf16* __restrict__ QKT, const __bf16* __restrict__ WHV,
    const __bf16* __restrict__ RKT,
    const float* __restrict__ rwb, const float* __restrict__ rrb,
    __bf16* __restrict__ AVt)
{
    __shared__ __bf16 SM[51712];
    __bf16* KT0 = SM;
    __bf16* KT1 = SM + 4096;
    __bf16* VS0 = SM + 8192;
    __bf16* VS1 = SM + 12288;
    __bf16* RT  = SM + 16384;      // [256][64] sw ring
    __bf16* PS  = SM + 32768;      // [128][64] sw
    __bf16* BT  = SM + 40960;      // per-wave [16][84]

    const int d = blockIdx.x;
    const int xcd = d & 7, idx = d >> 3;
    const int qt = idx & 7;
    const int gq = xcd + 8 * (idx >> 3);
    const int b = gq >> 4, n = gq & 15;
    const int i0 = qt * 128;

    const int t = threadIdx.x;
    const int lane = t & 63, w = t >> 6;
    const int l15 = lane & 15, lg = lane >> 4;
    const int g = w >> 2, wg = w & 3;
    const int fco = n * 64;

    const __bf16* qkb = QKT + (long long)b * (2048 * 2048);
    const __bf16* vb  = WHV + (long long)b * (1024 * 2048) + (long long)fco * 2048;
    __bf16* BTw = BT + w * 1344;

    #pragma unroll
    for (int pp = 0; pp < 2; ++pp) {
        int cid = pp * 512 + t;
        int q = cid >> 3, s = cid & 7, c = s ^ (q & 7);
        bf16x8 qv = *(const bf16x8*)&qkb[(long long)(1024 + i0 + q) * 2048 + fco + c * 8];
        bf16x8 ow, orr;
        #pragma unroll
        for (int e = 0; e < 8; ++e) {
            float qf = (float)qv[e];
            ow[e]  = (__bf16)(qf + rwb[fco + c * 8 + e]);
            orr[e] = (__bf16)(qf + rrb[fco + c * 8 + e]);
        }
        *(bf16x8*)&PS[q * 64 + s * 8] = ow;
        *(bf16x8*)&RT[q * 64 + s * 8] = orr;
    }
    __syncthreads();

    #define LDF(buf, row, ch) (*(const bf16x8*)&(buf)[(row) * 64 + ((((ch) ^ ((row) & 7))) * 8)])

    const int mrow = w * 16 + l15;
    bf16x8 qw0 = LDF(PS, mrow, lg), qw1 = LDF(PS, mrow, lg + 4);
    bf16x8 qr0 = LDF(RT, mrow, lg), qr1 = LDF(RT, mrow, lg + 4);
    asm volatile("s_waitcnt lgkmcnt(0)" ::: "memory");
    __builtin_amdgcn_sched_barrier(0);
    __builtin_amdgcn_s_barrier();

    {
        int r = t >> 3, s = t & 7, c = s ^ (r & 7);
        gload16(&qkb[(long long)(i0 + r) * 2048 + 1024 + fco + c * 8], &KT0[(w * 8) * 64]);
        gload16(&vb[(long long)r * 2048 + i0 + c * 8], &VS0[(w * 8) * 64]);
        #pragma unroll
        for (int pp = 0; pp < 3; ++pp) {
            int cid = pp * 512 + t;
            int rr = cid >> 3, ss = cid & 7, cc = ss ^ (rr & 7);
            gload16(&RKT[(long long)rr * 1024 + fco + cc * 8], &RT[(pp * 64 + w * 8) * 64]);
        }
    }
    asm volatile("s_waitcnt vmcnt(0)" ::: "memory");
    __builtin_amdgcn_sched_barrier(0);
    __builtin_amdgcn_s_barrier();

    const bf16x8 ones = { (__bf16)1.f, (__bf16)1.f, (__bf16)1.f, (__bf16)1.f,
                          (__bf16)1.f, (__bf16)1.f, (__bf16)1.f, (__bf16)1.f };

    f32x4 O0 = {}, O1 = {}, O2 = {}, O3 = {};
    float rm[4] = {-1e30f, -1e30f, -1e30f, -1e30f};
    float rl[4] = {0.f, 0.f, 0.f, 0.f};
    int cur = 0;

    for (int kt = 0; kt <= 17; ++kt) {
        __bf16* KTc = cur ? KT1 : KT0;
        __bf16* VSc = cur ? VS1 : VS0;
        __bf16* KTn = cur ? KT0 : KT1;
        __bf16* VSn = cur ? VS0 : VS1;
        const int ktr = kt - g;

        if (kt < 17) {
            int j0n = i0 + (kt + 1) * 64;
            int r = t >> 3, s = t & 7, c = s ^ (r & 7);
            gload16(&qkb[(long long)(j0n + r) * 2048 + 1024 + fco + c * 8], &KTn[(w * 8) * 64]);
            gload16(&vb[(long long)r * 2048 + j0n + c * 8], &VSn[(w * 8) * 64]);
        }
        if (kt < 16) {
            int rb = kt * 64 + 128;
            int lb = ((kt + 2) & 3) * 64;
            int r = t >> 3, s = t & 7, c = s ^ (r & 7);
            gload16(&RKT[(long long)(rb + r) * 1024 + fco + c * 8], &RT[(lb + w * 8) * 64]);
        }
        __builtin_amdgcn_sched_barrier(0);

        __builtin_amdgcn_s_setprio(1);
        #pragma unroll
        for (int k5 = 0; k5 < 5; ++k5) {
            int pr = (3 - wg + k5) * 16 + l15;
            int lr = ((ktr * 64) + pr) & 255;
            const __bf16* rrow = &RT[lr * 64];
            f32x4 cc = {};
            cc = __builtin_amdgcn_mfma_f32_16x16x32_bf16(qr0, *(const bf16x8*)&rrow[((lg ^ (pr & 7)) * 8)], cc, 0, 0, 0);
            cc = __builtin_amdgcn_mfma_f32_16x16x32_bf16(qr1, *(const bf16x8*)&rrow[(((lg + 4) ^ (pr & 7)) * 8)], cc, 0, 0, 0);
            #pragma unroll
            for (int rg = 0; rg < 4; ++rg)
                BTw[(lg * 4 + rg) * 84 + k5 * 16 + l15] = (__bf16)cc[rg];
        }
        __builtin_amdgcn_s_setprio(0);

        f32x4 cc4[4];
        __builtin_amdgcn_s_setprio(1);
        #pragma unroll
        for (int nt = 0; nt < 4; ++nt) {
            int jr = nt * 16 + l15;
            f32x4 cc = {};
            cc = __builtin_amdgcn_mfma_f32_16x16x32_bf16(qw0, LDF(KTc, jr, lg), cc, 0, 0, 0);
            cc = __builtin_amdgcn_mfma_f32_16x16x32_bf16(qw1, LDF(KTc, jr, lg + 4), cc, 0, 0, 0);
            cc4[nt] = cc;
        }
        __builtin_amdgcn_s_setprio(0);

        const bool bnd = (ktr <= 1) | (ktr >= 16);
        float sv[4][4];
        if (!bnd) {
            #pragma unroll
            for (int nt = 0; nt < 4; ++nt) {
                int jr = nt * 16 + l15;
                #pragma unroll
                for (int rg = 0; rg < 4; ++rg) {
                    int r4 = lg * 4 + rg;
                    sv[nt][rg] = (cc4[nt][rg] + (float)BTw[r4 * 84 + jr - r4 + 15]) * 0.125f;
                }
            }
        } else {
            #pragma unroll
            for (int nt = 0; nt < 4; ++nt) {
                int jr = nt * 16 + l15;
                #pragma unroll
                for (int rg = 0; rg < 4; ++rg) {
                    int r4 = lg * 4 + rg;
                    int dji = jr - (wg * 16 + r4);
                    float s = (cc4[nt][rg] + (float)BTw[r4 * 84 + jr - r4 + 15]) * 0.125f;
                    bool valid = (ktr == 0) ? (dji >= 25)
                               : (ktr == 1) ? (dji >= -39)
                               : (ktr == 16) ? (dji <= 0) : false;
                    sv[nt][rg] = valid ? s : -1e30f;
                }
            }
        }

        float lmax[4];
        bool need = false;
        #pragma unroll
        for (int rg = 0; rg < 4; ++rg) {
            lmax[rg] = fmaxf(fmaxf(sv[0][rg], sv[1][rg]), fmaxf(sv[2][rg], sv[3][rg]));
            need = need || (lmax[rg] > rm[rg] + 8.0f);
        }
        if (__any(need)) {
            #pragma unroll
            for (int rg = 0; rg < 4; ++rg) {
                float m = lmax[rg];
                m = fmaxf(m, __shfl_xor(m, 1, 16));
                m = fmaxf(m, __shfl_xor(m, 2, 16));
                m = fmaxf(m, __shfl_xor(m, 4, 16));
                m = fmaxf(m, __shfl_xor(m, 8, 16));
                float nm = fmaxf(rm[rg], m);
                float fac = __expf(rm[rg] - nm);
                rm[rg] = nm;
                rl[rg] *= fac;
                O0[rg] *= fac; O1[rg] *= fac; O2[rg] *= fac; O3[rg] *= fac;
            }
        }

        if (!bnd) {
            #pragma unroll
            for (int nt = 0; nt < 4; ++nt) {
                int jc = nt * 16 + l15;
                #pragma unroll
                for (int rg = 0; rg < 4; ++rg) {
                    float p = __expf(sv[nt][rg] - rm[rg]);
                    int row = w * 16 + lg * 4 + rg;
                    PS[row * 64 + (((jc >> 3) ^ (row & 7)) * 8) + (jc & 7)] = (__bf16)p;
                }
            }
        } else {
            #pragma unroll
            for (int nt = 0; nt < 4; ++nt) {
                int jc = nt * 16 + l15;
                #pragma unroll
                for (int rg = 0; rg < 4; ++rg) {
                    float p = (sv[nt][rg] > -1e29f) ? __expf(sv[nt][rg] - rm[rg]) : 0.0f;
                    int row = w * 16 + lg * 4 + rg;
                    PS[row * 64 + (((jc >> 3) ^ (row & 7)) * 8) + (jc & 7)] = (__bf16)p;
                }
            }
        }

        bf16x8 pa0 = LDF(PS, mrow, lg), pa1 = LDF(PS, mrow, lg + 4);
        f32x4 Os = {};
        __builtin_amdgcn_s_setprio(1);
        Os = __builtin_amdgcn_mfma_f32_16x16x32_bf16(pa0, ones, Os, 0, 0, 0);
        Os = __builtin_amdgcn_mfma_f32_16x16x32_bf16(pa1, ones, Os, 0, 0, 0);
        O0 = __builtin_amdgcn_mfma_f32_16x16x32_bf16(pa0, LDF(VSc,  0 + l15, lg),     O0, 0, 0, 0);
        O0 = __builtin_amdgcn_mfma_f32_16x16x32_bf16(pa1, LDF(VSc,  0 + l15, lg + 4), O0, 0, 0, 0);
        O1 = __builtin_amdgcn_mfma_f32_16x16x32_bf16(pa0, LDF(VSc, 16 + l15, lg),     O1, 0, 0, 0);
        O1 = __builtin_amdgcn_mfma_f32_16x16x32_bf16(pa1, LDF(VSc, 16 + l15, lg + 4), O1, 0, 0, 0);
        O2 = __builtin_amdgcn_mfma_f32_16x16x32_bf16(pa0, LDF(VSc, 32 + l15, lg),     O2, 0, 0, 0);
        O2 = __builtin_amdgcn_mfma_f32_16x16x32_bf16(pa1, LDF(VSc, 32 + l15, lg + 4), O2, 0, 0, 0);
        O3 = __builtin_amdgcn_mfma_f32_16x16x32_bf16(pa0, LDF(VSc, 48 + l15, lg),     O3, 0, 0, 0);
        O3 = __builtin_amdgcn_mfma_f32_16x16x32_bf16(pa1, LDF(VSc, 48 + l15, lg + 4), O3, 0, 0, 0);
        __builtin_amdgcn_s_setprio(0);
        #pragma unroll
        for (int rg = 0; rg < 4; ++rg) rl[rg] += Os[rg];

        asm volatile("s_waitcnt vmcnt(0)" ::: "memory");
        __builtin_amdgcn_sched_barrier(0);
        __builtin_amdgcn_s_barrier();
        cur ^= 1;
    }

    #pragma unroll
    for (int rg = 0; rg < 4; ++rg) {
        float inv = 1.0f / rl[rg];
        int q = i0 + w * 16 + lg * 4 + rg;
        long long base = ((long long)b * 1024 + q) * 1024 + fco;
        AVt[base +  0 + l15] = (__bf16)(O0[rg] * inv);
        AVt[base + 16 + l15] = (__bf16)(O1[rg] * inv);
        AVt[base + 32 + l15] = (__bf16)(O2[rg] * inv);
        AVt[base + 48 + l15] = (__bf16)(O3[rg] * inv);
    }
    #undef LDF
}

// ================= LN1: 2 partials + bo + z =================
__global__ __launch_bounds__(256) void ln1_kernel(
    const float* __restrict__ A0, const float* __restrict__ A1,
    const float* __restrict__ bo, const __bf16* __restrict__ CatT,
    __bf16* __restrict__ Hb)
{
    int i = blockIdx.x, b = blockIdx.y, t = threadIdx.x;
    __shared__ float xs[D_MODEL];
    __shared__ float red[256];
    __shared__ float smu, srstd;
    long long tb = ((long long)b * 1024 + i) * 1024;
    long long zb = ((long long)b * 2048 + 1024 + i) * 1024;

    float lsum = 0.0f;
    for (int dd = t; dd < D_MODEL; dd += 256) {
        float v = A0[tb + dd] + A1[tb + dd] + bo[dd] + (float)CatT[zb + dd];
        xs[dd] = v;
        lsum += v;
    }
    red[t] = lsum; __syncthreads();
    for (int s2 = 128; s2 > 0; s2 >>= 1) { if (t < s2) red[t] += red[t + s2]; __syncthreads(); }
    if (t == 0) smu = red[0] * (1.0f / D_MODEL);
    __syncthreads();
    float mu = smu;

    float lq = 0.0f;
    for (int dd = t; dd < D_MODEL; dd += 256) { float c = xs[dd] - mu; lq += c * c; }
    red[t] = lq; __syncthreads();
    for (int s2 = 128; s2 > 0; s2 >>= 1) { if (t < s2) red[t] += red[t + s2]; __syncthreads(); }
    if (t == 0) srstd = rsqrtf(red[0] * (1.0f / D_MODEL) + 1e-5f);
    __syncthreads();
    float rstd = srstd;

    for (int dd = t; dd < D_MODEL; dd += 256)
        Hb[tb + dd] = (__bf16)((xs[dd] - mu) * rstd);
}

// ================= LN2 stats (2 partials + h) =================
__global__ __launch_bounds__(256) void ln2_stats(
    const float* __restrict__ F0, const float* __restrict__ F1,
    const __bf16* __restrict__ Hb, float2* __restrict__ st)
{
    int i = blockIdx.x, b = blockIdx.y, t = threadIdx.x;
    __shared__ float rs[256], rq[256];
    long long tb = ((long long)b * 1024 + i) * 1024;

    float s = 0.f, q = 0.f;
    for (int dd = t; dd < D_MODEL; dd += 256) {
        float v = F0[tb + dd] + F1[tb + dd] + (float)Hb[tb + dd];
        s += v; q += v * v;
    }
    rs[t] = s; rq[t] = q; __syncthreads();
    for (int s2 = 128; s2 > 0; s2 >>= 1) {
        if (t < s2) { rs[t] += rs[t + s2]; rq[t] += rq[t + s2]; }
        __syncthreads();
    }
    if (t == 0) {
        float mu = rs[0] * (1.0f / D_MODEL);
        float var = rq[0] * (1.0f / D_MODEL) - mu * mu;
        st[(long long)b * 1024 + i] = make_float2(mu, rsqrtf(var + 1e-5f));
    }
}

// ================= LN2 transposed write =================
__global__ __launch_bounds__(256) void ln2_write(
    const float* __restrict__ F0, const float* __restrict__ F1,
    const __bf16* __restrict__ Hb, const float2* __restrict__ st,
    float* __restrict__ OUT)
{
    __shared__ float ts[32][33];
    int f0 = blockIdx.x * 32, i0 = blockIdx.y * 32, b = blockIdx.z;
    int tr = threadIdx.x >> 5, tc = threadIdx.x & 31;
    #pragma unroll
    for (int p = 0; p < 4; ++p) {
        int tok = i0 + tr + p * 8;
        long long tb = ((long long)b * 1024 + tok) * 1024;
        float2 s = st[(long long)b * 1024 + tok];
        float v = F0[tb + f0 + tc] + F1[tb + f0 + tc] + (float)Hb[tb + f0 + tc];
        ts[tr + p * 8][tc] = (v - s.x) * s.y;
    }
    __syncthreads();
    #pragma unroll
    for (int p = 0; p < 4; ++p)
        OUT[((long long)b * 1024 + f0 + tr + p * 8) * 1024 + i0 + tc] = ts[tc][tr + p * 8];
}

// ================= launch =================
extern "C" void kernel_launch(void* const* d_in, const int* in_sizes, int n_in,
                              void* d_out, int out_size, void* d_ws, size_t ws_size,
                              hipStream_t stream) {
    const float* z    = (const float*)d_in[0];
    const float* zh   = (const float*)d_in[1];
    const float* u    = (const float*)d_in[2];
    const float* pos  = (const float*)d_in[3];
    const float* Wqkv = (const float*)d_in[4];
    const float* Wr   = (const float*)d_in[5];
    const float* rwb  = (const float*)d_in[6];
    const float* rrb  = (const float*)d_in[7];
    const float* Wo   = (const float*)d_in[8];
    const float* bo   = (const float*)d_in[9];
    const float* Wff1 = (const float*)d_in[10];
    const float* bff1 = (const float*)d_in[11];
    const float* Wff2 = (const float*)d_in[12];
    const float* bff2 = (const float*)d_in[13];
    float* out = (float*)d_out;
    float* ws  = (float*)d_ws;

    __bf16* cat_t = (__bf16*)ws;
    __bf16* pos_t = (__bf16*)(ws + 2097152);
    __bf16* Wqkvb = (__bf16*)(ws + 3178496);
    __bf16* Wrb   = (__bf16*)(ws + 4751360);
    __bf16* Wob   = (__bf16*)(ws + 5275648);
    __bf16* Wff1b = (__bf16*)(ws + 5799936);
    __bf16* Wff2b = (__bf16*)(ws + 7897088);
    __bf16* qkT   = (__bf16*)(ws + 14188544);
    __bf16* wh_v  = (__bf16*)(ws + 18382848);
    __bf16* rkT   = (__bf16*)(ws + 20480000);
    __bf16* av_t  = (__bf16*)(ws + 21069824);
    float*  ao0   = ws + 22118400;
    float*  ao1   = ws + 24215552;
    __bf16* h_bf  = (__bf16*)(ws + 26312704);
    float2* st2   = (float2*)(ws + 27361280);
    __bf16* f1b   = (__bf16*)(ws + 14188544);
    float*  f20   = ws + 9994240;
    float*  f21   = ws + 12091392;

    prep_all<<<19520, 256, 0, stream>>>(
        Wqkv, Wqkvb, Wr, Wrb, Wo, Wob, Wff1, Wff1b, Wff2, Wff2b,
        zh, z, cat_t, pos, pos_t);

    gemm_fused3<<<840, 512, 0, stream>>>(
        cat_t, Wqkvb, qkT, u, wh_v, pos_t, Wrb, rkT);

    attn_mfma<<<256, 512, 0, stream>>>(qkT, wh_v, rkT, rwb, rrb, av_t);

    gemm_bf16_k<2><<<dim3(8, 32, 1), 512, 0, stream>>>(
        av_t, Wob, ao0, ao1, nullptr, nullptr, nullptr,
        1024, 1024, 1024, 1024, 0, 0);
    ln1_kernel<<<dim3(1024, 2), 256, 0, stream>>>(ao0, ao1, bo, cat_t, h_bf);
    gemm_bf16_k<1><<<dim3(32, 16, 1), 512, 0, stream>>>(
        h_bf, Wff1b, nullptr, nullptr, f1b, nullptr, bff1,
        1024, 1024, 1024, 4096, 0, 1);
    gemm_bf16_k<2><<<dim3(8, 32, 1), 512, 0, stream>>>(
        f1b, Wff2b, f20, f21, nullptr, nullptr, bff2,
        4096, 4096, 4096, 1024, 0, 0);
    ln2_stats<<<dim3(1024, 2), 256, 0, stream>>>(f20, f21, h_bf, st2);
    ln2_write<<<dim3(32, 32, 2), 256, 0, stream>>>(f20, f21, h_bf, st2, out);
}

// Round 20
// 203.944 us; speedup vs baseline: 1.0205x; 1.0205x over previous
//
#include <hip/hip_runtime.h>

#define D_MODEL 1024
#define QLEN 1024

typedef __bf16 bf16x8 __attribute__((ext_vector_type(8)));
typedef __bf16 bf16x4 __attribute__((ext_vector_type(4)));
typedef float f32x4 __attribute__((ext_vector_type(4)));

__device__ __forceinline__ void gload16(const void* g, void* l) {
    __builtin_amdgcn_global_load_lds(
        (const __attribute__((address_space(1))) void*)g,
        (__attribute__((address_space(3))) void*)l, 16, 0, 0);
}

// ============ GEMM core, 8 waves / 512 threads: C tile 128x128 at (m0,n0) ============
// U: fp32 addend, C layout. Ut: fp32 addend, TRANSPOSED layout — staged via LDS.
__device__ __forceinline__ void gemm_core8(
    __bf16* __restrict__ smA, __bf16* __restrict__ smB,
    const __bf16* __restrict__ A, const __bf16* __restrict__ Bt,
    float* __restrict__ C, __bf16* __restrict__ Cb,
    const float* __restrict__ U, const float* __restrict__ Ut,
    const float* __restrict__ bias,
    int K, int lda, int ldb, int ldC, int ldU, int relu, int m0, int n0)
{
    const int t = threadIdx.x;
    const int lane = t & 63, w = t >> 6;
    const int l15 = lane & 15, lg = lane >> 4;
    const int wm = w >> 2, wn = w & 3;
    const int srow = lane >> 3, cpr = lane & 7;
    const int NK = K >> 6;
    const int SZ = 128 * 64;

    #define STAGE(buf, kt)                                                                   \
    {                                                                                        \
        int k0s = (kt) * 64;                                                                 \
        _Pragma("unroll")                                                                    \
        for (int i = 0; i < 2; ++i) {                                                        \
            int r = w * 16 + i * 8 + srow;                                                   \
            int c = cpr ^ (r & 7);                                                           \
            gload16(&A[(long long)(m0 + r) * lda + k0s + c * 8],                             \
                    &smA[(buf) * SZ + (w * 16 + i * 8) * 64]);                               \
            gload16(&Bt[(long long)(n0 + r) * ldb + k0s + c * 8],                            \
                    &smB[(buf) * SZ + (w * 16 + i * 8) * 64]);                               \
        }                                                                                    \
    }

    f32x4 acc[4][2] = {};
    STAGE(0, 0);

    for (int kt = 0; kt < NK; ++kt) {
        const int cb = kt & 1;
        if (kt + 1 < NK) {
            STAGE(cb ^ 1, kt + 1);
            asm volatile("s_waitcnt vmcnt(4)" ::: "memory");
        } else {
            asm volatile("s_waitcnt vmcnt(0)" ::: "memory");
        }
        __builtin_amdgcn_sched_barrier(0);
        __builtin_amdgcn_s_barrier();

        #pragma unroll
        for (int kk = 0; kk < 2; ++kk) {
            bf16x8 bfr[2];
            #pragma unroll
            for (int nt = 0; nt < 2; ++nt) {
                int nr = wn * 32 + nt * 16 + l15;
                bfr[nt] = *(const bf16x8*)&smB[cb * SZ + nr * 64 + (((kk * 4 + lg) ^ (nr & 7)) * 8)];
            }
            #pragma unroll
            for (int mt = 0; mt < 4; ++mt) {
                int mr = wm * 64 + mt * 16 + l15;
                bf16x8 afr = *(const bf16x8*)&smA[cb * SZ + mr * 64 + (((kk * 4 + lg) ^ (mr & 7)) * 8)];
                #pragma unroll
                for (int nt = 0; nt < 2; ++nt)
                    acc[mt][nt] = __builtin_amdgcn_mfma_f32_16x16x32_bf16(afr, bfr[nt], acc[mt][nt], 0, 0, 0);
            }
        }
        asm volatile("s_waitcnt lgkmcnt(0)" ::: "memory");
        __builtin_amdgcn_sched_barrier(0);
        __builtin_amdgcn_s_barrier();
    }
    #undef STAGE

    if (Ut) {
        float* uf = (float*)smA;
        #pragma unroll
        for (int hh = 0; hh < 2; ++hh) {
            __syncthreads();
            int r = t >> 3, c0 = (t & 7) * 16;
            const float* src = &Ut[(long long)(n0 + hh * 64 + r) * ldU + m0 + c0];
            #pragma unroll
            for (int k = 0; k < 4; ++k)
                *(float4*)&uf[r * 132 + c0 + k * 4] = *(const float4*)&src[k * 4];
            __syncthreads();
            if ((wn >> 1) == hh) {
                #pragma unroll
                for (int nt = 0; nt < 2; ++nt) {
                    int rr = wn * 32 + nt * 16 + l15 - hh * 64;
                    #pragma unroll
                    for (int mt = 0; mt < 4; ++mt) {
                        #pragma unroll
                        for (int rg = 0; rg < 4; ++rg) {
                            int m = wm * 64 + mt * 16 + lg * 4 + rg;
                            acc[mt][nt][rg] += uf[rr * 132 + m];
                        }
                    }
                }
            }
        }
    }

    #pragma unroll
    for (int mt = 0; mt < 4; ++mt) {
        #pragma unroll
        for (int nt = 0; nt < 2; ++nt) {
            #pragma unroll
            for (int rg = 0; rg < 4; ++rg) {
                int m = m0 + wm * 64 + mt * 16 + lg * 4 + rg;
                int n = n0 + wn * 32 + nt * 16 + l15;
                float v = acc[mt][nt][rg];
                if (U)    v += U[(long long)m * ldU + n];
                if (bias) v += bias[n];
                if (relu) v = fmaxf(v, 0.0f);
                if (Cb) Cb[(long long)m * ldC + n] = (__bf16)v;
                else    C [(long long)m * ldC + n] = v;
            }
        }
    }
}

// ============ generic wrapper, KSPLIT-way K-split ============
template<int KSPLIT>
__global__ __launch_bounds__(512) void gemm_bf16_k(
    const __bf16* __restrict__ A, const __bf16* __restrict__ Bt,
    float* __restrict__ C0, float* __restrict__ C1,
    __bf16* __restrict__ Cb,
    const float* __restrict__ U, const float* __restrict__ bias,
    int K, int lda, int ldb, int ldC, int ldU, int relu)
{
    __shared__ __bf16 SM[32768];
    int yb = blockIdx.y;
    int half = 0;
    if (KSPLIT > 1) { half = yb & (KSPLIT - 1); yb /= KSPLIT; }
    const int Keff = K / KSPLIT;
    A  += (long long)half * Keff;
    Bt += (long long)half * Keff;
    float* C = half ? C1 : C0;
    if (half) { bias = nullptr; U = nullptr; }
    gemm_core8(SM, SM + 16384, A, Bt, C, Cb, U, nullptr, bias,
               Keff, lda, ldb, ldC, ldU, relu, yb * 128, blockIdx.x * 128);
}

// ============ fused 3-job GEMM: qkT (512, +u^T via LDS) + wh_v (256) + rkT (72) ============
__global__ __launch_bounds__(512) void gemm_fused3(
    const __bf16* __restrict__ cat_t, const __bf16* __restrict__ Wqkvb,
    __bf16* __restrict__ qkT, const float* __restrict__ u,
    __bf16* __restrict__ wh_v,
    const __bf16* __restrict__ pos_t, const __bf16* __restrict__ Wrb,
    __bf16* __restrict__ rkT)
{
    __shared__ __bf16 SM[32768];
    int bid = blockIdx.x;
    if (bid < 512) {
        int zz = bid >> 8, rem = bid & 255, y = rem >> 4, x = rem & 15;
        gemm_core8(SM, SM + 16384,
                   cat_t + (long long)zz * 2097152, Wqkvb,
                   nullptr, qkT + (long long)zz * 4194304,
                   nullptr, u + (long long)zz * 6291456, nullptr,
                   1024, 1024, 1024, 2048, 2048, 0, y * 128, x * 128);
    } else if (bid < 768) {
        int l = bid - 512, zz = l >> 7, rem = l & 127, y = rem >> 4, x = rem & 15;
        gemm_core8(SM, SM + 16384,
                   Wqkvb + 2048 * 1024, cat_t + (long long)zz * 2097152,
                   nullptr, wh_v + (long long)zz * 2097152,
                   u + 4194304 + (long long)zz * 6291456, nullptr, nullptr,
                   1024, 1024, 1024, 2048, 2048, 0, y * 128, x * 128);
    } else {
        int l = bid - 768, y = l >> 3, x = l & 7;
        gemm_core8(SM, SM + 16384,
                   pos_t + 960 * 1024, Wrb,
                   nullptr, rkT, nullptr, nullptr, nullptr,
                   1024, 1024, 1024, 1024, 0, 0, y * 128, x * 128);
    }
}

// ============ fused prep: weight converts + 3 transposes + pos pad ============
__global__ __launch_bounds__(256) void prep_all(
    const float* __restrict__ Wqkv, __bf16* __restrict__ Wqkvb,
    const float* __restrict__ Wr,   __bf16* __restrict__ Wrb,
    const float* __restrict__ Wo,   __bf16* __restrict__ Wob,
    const float* __restrict__ Wff1, __bf16* __restrict__ Wff1b,
    const float* __restrict__ Wff2, __bf16* __restrict__ Wff2b,
    const float* __restrict__ zh, const float* __restrict__ z, __bf16* __restrict__ cat_t,
    const float* __restrict__ pos, __bf16* __restrict__ pos_t)
{
    __shared__ float ts[32][33];
    int bid = blockIdx.x;
    const int t = threadIdx.x;
    if (bid < 13312) {
        long long i = ((long long)bid * 256 + t) * 4;
        const float* s; __bf16* dd;
        if (i < 3145728)                    { s = Wqkv + i; dd = Wqkvb + i; }
        else if ((i -= 3145728) < 1048576)  { s = Wr + i;   dd = Wrb + i; }
        else if ((i -= 1048576) < 1048576)  { s = Wo + i;   dd = Wob + i; }
        else if ((i -= 1048576) < 4194304)  { s = Wff1 + i; dd = Wff1b + i; }
        else { i -= 4194304;                  s = Wff2 + i; dd = Wff2b + i; }
        float4 v = *(const float4*)s;
        bf16x4 o = { (__bf16)v.x, (__bf16)v.y, (__bf16)v.z, (__bf16)v.w };
        *(bf16x4*)dd = o;
        return;
    }
    bid -= 13312;
    const float* S; __bf16* D; int R, Cc, bx, by;
    if (bid < 2048) {
        int zz = bid >> 10, r2 = bid & 1023;
        S = zh + (long long)zz * 1048576; D = cat_t + (long long)zz * 2097152;
        R = 1024; Cc = 1024; bx = r2 & 31; by = r2 >> 5;
    } else if (bid < 4096) {
        int l = bid - 2048; int zz = l >> 10, r2 = l & 1023;
        S = z + (long long)zz * 1048576; D = cat_t + 1048576 + (long long)zz * 2097152;
        R = 1024; Cc = 1024; bx = r2 & 31; by = r2 >> 5;
    } else if (bid < 6144) {
        int l = bid - 4096;
        S = pos; D = pos_t; R = 1024; Cc = 2048; bx = l & 63; by = l >> 6;
    } else {
        int l = bid - 6144;
        int i = (l * 256 + t) * 4;
        bf16x4 zv = { (__bf16)0.f, (__bf16)0.f, (__bf16)0.f, (__bf16)0.f };
        *(bf16x4*)&pos_t[2048 * 1024 + i] = zv;
        return;
    }
    int r0 = by * 32, c0 = bx * 32;
    int tr = t >> 5, tc = t & 31;
    #pragma unroll
    for (int p = 0; p < 4; ++p)
        ts[tr + p * 8][tc] = S[(long long)(r0 + tr + p * 8) * Cc + c0 + tc];
    __syncthreads();
    #pragma unroll
    for (int p = 0; p < 4; ++p)
        D[(long long)(c0 + tr + p * 8) * R + r0 + tc] = (__bf16)ts[tc][tr + p * 8];
}

// ================= MFMA flash attention: 128-q blocks, 8 waves, shared staging =================
__global__ __launch_bounds__(512) void attn_mfma(
    const __bf16* __restrict__ QKT, const __bf16* __restrict__ WHV,
    const __bf16* __restrict__ RKT,
    const float* __restrict__ rwb, const float* __restrict__ rrb,
    __bf16* __restrict__ AVt)
{
    __shared__ __bf16 SM[51712];
    __bf16* KT0 = SM;
    __bf16* KT1 = SM + 4096;
    __bf16* VS0 = SM + 8192;
    __bf16* VS1 = SM + 12288;
    __bf16* RT  = SM + 16384;      // [256][64] sw ring
    __bf16* PS  = SM + 32768;      // [128][64] sw
    __bf16* BT  = SM + 40960;      // per-wave [16][84]

    const int d = blockIdx.x;
    const int xcd = d & 7, idx = d >> 3;
    const int qt = idx & 7;
    const int gq = xcd + 8 * (idx >> 3);
    const int b = gq >> 4, n = gq & 15;
    const int i0 = qt * 128;

    const int t = threadIdx.x;
    const int lane = t & 63, w = t >> 6;
    const int l15 = lane & 15, lg = lane >> 4;
    const int g = w >> 2, wg = w & 3;
    const int fco = n * 64;

    const __bf16* qkb = QKT + (long long)b * (2048 * 2048);
    const __bf16* vb  = WHV + (long long)b * (1024 * 2048) + (long long)fco * 2048;
    __bf16* BTw = BT + w * 1344;

    #pragma unroll
    for (int pp = 0; pp < 2; ++pp) {
        int cid = pp * 512 + t;
        int q = cid >> 3, s = cid & 7, c = s ^ (q & 7);
        bf16x8 qv = *(const bf16x8*)&qkb[(long long)(1024 + i0 + q) * 2048 + fco + c * 8];
        bf16x8 ow, orr;
        #pragma unroll
        for (int e = 0; e < 8; ++e) {
            float qf = (float)qv[e];
            ow[e]  = (__bf16)(qf + rwb[fco + c * 8 + e]);
            orr[e] = (__bf16)(qf + rrb[fco + c * 8 + e]);
        }
        *(bf16x8*)&PS[q * 64 + s * 8] = ow;
        *(bf16x8*)&RT[q * 64 + s * 8] = orr;
    }
    __syncthreads();

    #define LDF(buf, row, ch) (*(const bf16x8*)&(buf)[(row) * 64 + ((((ch) ^ ((row) & 7))) * 8)])

    const int mrow = w * 16 + l15;
    bf16x8 qw0 = LDF(PS, mrow, lg), qw1 = LDF(PS, mrow, lg + 4);
    bf16x8 qr0 = LDF(RT, mrow, lg), qr1 = LDF(RT, mrow, lg + 4);
    asm volatile("s_waitcnt lgkmcnt(0)" ::: "memory");
    __builtin_amdgcn_sched_barrier(0);
    __builtin_amdgcn_s_barrier();

    {
        int r = t >> 3, s = t & 7, c = s ^ (r & 7);
        gload16(&qkb[(long long)(i0 + r) * 2048 + 1024 + fco + c * 8], &KT0[(w * 8) * 64]);
        gload16(&vb[(long long)r * 2048 + i0 + c * 8], &VS0[(w * 8) * 64]);
        #pragma unroll
        for (int pp = 0; pp < 3; ++pp) {
            int cid = pp * 512 + t;
            int rr = cid >> 3, ss = cid & 7, cc = ss ^ (rr & 7);
            gload16(&RKT[(long long)rr * 1024 + fco + cc * 8], &RT[(pp * 64 + w * 8) * 64]);
        }
    }
    asm volatile("s_waitcnt vmcnt(0)" ::: "memory");
    __builtin_amdgcn_sched_barrier(0);
    __builtin_amdgcn_s_barrier();

    const bf16x8 ones = { (__bf16)1.f, (__bf16)1.f, (__bf16)1.f, (__bf16)1.f,
                          (__bf16)1.f, (__bf16)1.f, (__bf16)1.f, (__bf16)1.f };

    f32x4 O0 = {}, O1 = {}, O2 = {}, O3 = {};
    float rm[4] = {-1e30f, -1e30f, -1e30f, -1e30f};
    float rl[4] = {0.f, 0.f, 0.f, 0.f};
    int cur = 0;

    for (int kt = 0; kt <= 17; ++kt) {
        __bf16* KTc = cur ? KT1 : KT0;
        __bf16* VSc = cur ? VS1 : VS0;
        __bf16* KTn = cur ? KT0 : KT1;
        __bf16* VSn = cur ? VS0 : VS1;
        const int ktr = kt - g;

        if (kt < 17) {
            int j0n = i0 + (kt + 1) * 64;
            int r = t >> 3, s = t & 7, c = s ^ (r & 7);
            gload16(&qkb[(long long)(j0n + r) * 2048 + 1024 + fco + c * 8], &KTn[(w * 8) * 64]);
            gload16(&vb[(long long)r * 2048 + j0n + c * 8], &VSn[(w * 8) * 64]);
        }
        if (kt < 16) {
            int rb = kt * 64 + 128;
            int lb = ((kt + 2) & 3) * 64;
            int r = t >> 3, s = t & 7, c = s ^ (r & 7);
            gload16(&RKT[(long long)(rb + r) * 1024 + fco + c * 8], &RT[(lb + w * 8) * 64]);
        }
        __builtin_amdgcn_sched_barrier(0);

        __builtin_amdgcn_s_setprio(1);
        #pragma unroll
        for (int k5 = 0; k5 < 5; ++k5) {
            int pr = (3 - wg + k5) * 16 + l15;
            int lr = ((ktr * 64) + pr) & 255;
            const __bf16* rrow = &RT[lr * 64];
            f32x4 cc = {};
            cc = __builtin_amdgcn_mfma_f32_16x16x32_bf16(qr0, *(const bf16x8*)&rrow[((lg ^ (pr & 7)) * 8)], cc, 0, 0, 0);
            cc = __builtin_amdgcn_mfma_f32_16x16x32_bf16(qr1, *(const bf16x8*)&rrow[(((lg + 4) ^ (pr & 7)) * 8)], cc, 0, 0, 0);
            #pragma unroll
            for (int rg = 0; rg < 4; ++rg)
                BTw[(lg * 4 + rg) * 84 + k5 * 16 + l15] = (__bf16)cc[rg];
        }
        __builtin_amdgcn_s_setprio(0);

        f32x4 cc4[4];
        __builtin_amdgcn_s_setprio(1);
        #pragma unroll
        for (int nt = 0; nt < 4; ++nt) {
            int jr = nt * 16 + l15;
            f32x4 cc = {};
            cc = __builtin_amdgcn_mfma_f32_16x16x32_bf16(qw0, LDF(KTc, jr, lg), cc, 0, 0, 0);
            cc = __builtin_amdgcn_mfma_f32_16x16x32_bf16(qw1, LDF(KTc, jr, lg + 4), cc, 0, 0, 0);
            cc4[nt] = cc;
        }
        __builtin_amdgcn_s_setprio(0);

        const bool bnd = (ktr <= 1) | (ktr >= 16);
        float sv[4][4];
        if (!bnd) {
            #pragma unroll
            for (int nt = 0; nt < 4; ++nt) {
                int jr = nt * 16 + l15;
                #pragma unroll
                for (int rg = 0; rg < 4; ++rg) {
                    int r4 = lg * 4 + rg;
                    sv[nt][rg] = (cc4[nt][rg] + (float)BTw[r4 * 84 + jr - r4 + 15]) * 0.125f;
                }
            }
        } else {
            #pragma unroll
            for (int nt = 0; nt < 4; ++nt) {
                int jr = nt * 16 + l15;
                #pragma unroll
                for (int rg = 0; rg < 4; ++rg) {
                    int r4 = lg * 4 + rg;
                    int dji = jr - (wg * 16 + r4);
                    float s = (cc4[nt][rg] + (float)BTw[r4 * 84 + jr - r4 + 15]) * 0.125f;
                    bool valid = (ktr == 0) ? (dji >= 25)
                               : (ktr == 1) ? (dji >= -39)
                               : (ktr == 16) ? (dji <= 0) : false;
                    sv[nt][rg] = valid ? s : -1e30f;
                }
            }
        }

        float lmax[4];
        bool need = false;
        #pragma unroll
        for (int rg = 0; rg < 4; ++rg) {
            lmax[rg] = fmaxf(fmaxf(sv[0][rg], sv[1][rg]), fmaxf(sv[2][rg], sv[3][rg]));
            need = need || (lmax[rg] > rm[rg] + 8.0f);
        }
        if (__any(need)) {
            #pragma unroll
            for (int rg = 0; rg < 4; ++rg) {
                float m = lmax[rg];
                m = fmaxf(m, __shfl_xor(m, 1, 16));
                m = fmaxf(m, __shfl_xor(m, 2, 16));
                m = fmaxf(m, __shfl_xor(m, 4, 16));
                m = fmaxf(m, __shfl_xor(m, 8, 16));
                float nm = fmaxf(rm[rg], m);
                float fac = __expf(rm[rg] - nm);
                rm[rg] = nm;
                rl[rg] *= fac;
                O0[rg] *= fac; O1[rg] *= fac; O2[rg] *= fac; O3[rg] *= fac;
            }
        }

        if (!bnd) {
            #pragma unroll
            for (int nt = 0; nt < 4; ++nt) {
                int jc = nt * 16 + l15;
                #pragma unroll
                for (int rg = 0; rg < 4; ++rg) {
                    float p = __expf(sv[nt][rg] - rm[rg]);
                    int row = w * 16 + lg * 4 + rg;
                    PS[row * 64 + (((jc >> 3) ^ (row & 7)) * 8) + (jc & 7)] = (__bf16)p;
                }
            }
        } else {
            #pragma unroll
            for (int nt = 0; nt < 4; ++nt) {
                int jc = nt * 16 + l15;
                #pragma unroll
                for (int rg = 0; rg < 4; ++rg) {
                    float p = (sv[nt][rg] > -1e29f) ? __expf(sv[nt][rg] - rm[rg]) : 0.0f;
                    int row = w * 16 + lg * 4 + rg;
                    PS[row * 64 + (((jc >> 3) ^ (row & 7)) * 8) + (jc & 7)] = (__bf16)p;
                }
            }
        }

        bf16x8 pa0 = LDF(PS, mrow, lg), pa1 = LDF(PS, mrow, lg + 4);
        f32x4 Os = {};
        __builtin_amdgcn_s_setprio(1);
        Os = __builtin_amdgcn_mfma_f32_16x16x32_bf16(pa0, ones, Os, 0, 0, 0);
        Os = __builtin_amdgcn_mfma_f32_16x16x32_bf16(pa1, ones, Os, 0, 0, 0);
        O0 = __builtin_amdgcn_mfma_f32_16x16x32_bf16(pa0, LDF(VSc,  0 + l15, lg),     O0, 0, 0, 0);
        O0 = __builtin_amdgcn_mfma_f32_16x16x32_bf16(pa1, LDF(VSc,  0 + l15, lg + 4), O0, 0, 0, 0);
        O1 = __builtin_amdgcn_mfma_f32_16x16x32_bf16(pa0, LDF(VSc, 16 + l15, lg),     O1, 0, 0, 0);
        O1 = __builtin_amdgcn_mfma_f32_16x16x32_bf16(pa1, LDF(VSc, 16 + l15, lg + 4), O1, 0, 0, 0);
        O2 = __builtin_amdgcn_mfma_f32_16x16x32_bf16(pa0, LDF(VSc, 32 + l15, lg),     O2, 0, 0, 0);
        O2 = __builtin_amdgcn_mfma_f32_16x16x32_bf16(pa1, LDF(VSc, 32 + l15, lg + 4), O2, 0, 0, 0);
        O3 = __builtin_amdgcn_mfma_f32_16x16x32_bf16(pa0, LDF(VSc, 48 + l15, lg),     O3, 0, 0, 0);
        O3 = __builtin_amdgcn_mfma_f32_16x16x32_bf16(pa1, LDF(VSc, 48 + l15, lg + 4), O3, 0, 0, 0);
        __builtin_amdgcn_s_setprio(0);
        #pragma unroll
        for (int rg = 0; rg < 4; ++rg) rl[rg] += Os[rg];

        asm volatile("s_waitcnt vmcnt(0)" ::: "memory");
        __builtin_amdgcn_sched_barrier(0);
        __builtin_amdgcn_s_barrier();
        cur ^= 1;
    }

    #pragma unroll
    for (int rg = 0; rg < 4; ++rg) {
        float inv = 1.0f / rl[rg];
        int q = i0 + w * 16 + lg * 4 + rg;
        long long base = ((long long)b * 1024 + q) * 1024 + fco;
        AVt[base +  0 + l15] = (__bf16)(O0[rg] * inv);
        AVt[base + 16 + l15] = (__bf16)(O1[rg] * inv);
        AVt[base + 32 + l15] = (__bf16)(O2[rg] * inv);
        AVt[base + 48 + l15] = (__bf16)(O3[rg] * inv);
    }
    #undef LDF
}

// ================= LN1: 2 partials + bo + z =================
__global__ __launch_bounds__(256) void ln1_kernel(
    const float* __restrict__ A0, const float* __restrict__ A1,
    const float* __restrict__ bo, const __bf16* __restrict__ CatT,
    __bf16* __restrict__ Hb)
{
    int i = blockIdx.x, b = blockIdx.y, t = threadIdx.x;
    __shared__ float xs[D_MODEL];
    __shared__ float red[256];
    __shared__ float smu, srstd;
    long long tb = ((long long)b * 1024 + i) * 1024;
    long long zb = ((long long)b * 2048 + 1024 + i) * 1024;

    float lsum = 0.0f;
    for (int dd = t; dd < D_MODEL; dd += 256) {
        float v = A0[tb + dd] + A1[tb + dd] + bo[dd] + (float)CatT[zb + dd];
        xs[dd] = v;
        lsum += v;
    }
    red[t] = lsum; __syncthreads();
    for (int s2 = 128; s2 > 0; s2 >>= 1) { if (t < s2) red[t] += red[t + s2]; __syncthreads(); }
    if (t == 0) smu = red[0] * (1.0f / D_MODEL);
    __syncthreads();
    float mu = smu;

    float lq = 0.0f;
    for (int dd = t; dd < D_MODEL; dd += 256) { float c = xs[dd] - mu; lq += c * c; }
    red[t] = lq; __syncthreads();
    for (int s2 = 128; s2 > 0; s2 >>= 1) { if (t < s2) red[t] += red[t + s2]; __syncthreads(); }
    if (t == 0) srstd = rsqrtf(red[0] * (1.0f / D_MODEL) + 1e-5f);
    __syncthreads();
    float rstd = srstd;

    for (int dd = t; dd < D_MODEL; dd += 256)
        Hb[tb + dd] = (__bf16)((xs[dd] - mu) * rstd);
}

// ================= LN2 stats (2 partials + h) =================
__global__ __launch_bounds__(256) void ln2_stats(
    const float* __restrict__ F0, const float* __restrict__ F1,
    const __bf16* __restrict__ Hb, float2* __restrict__ st)
{
    int i = blockIdx.x, b = blockIdx.y, t = threadIdx.x;
    __shared__ float rs[256], rq[256];
    long long tb = ((long long)b * 1024 + i) * 1024;

    float s = 0.f, q = 0.f;
    for (int dd = t; dd < D_MODEL; dd += 256) {
        float v = F0[tb + dd] + F1[tb + dd] + (float)Hb[tb + dd];
        s += v; q += v * v;
    }
    rs[t] = s; rq[t] = q; __syncthreads();
    for (int s2 = 128; s2 > 0; s2 >>= 1) {
        if (t < s2) { rs[t] += rs[t + s2]; rq[t] += rq[t + s2]; }
        __syncthreads();
    }
    if (t == 0) {
        float mu = rs[0] * (1.0f / D_MODEL);
        float var = rq[0] * (1.0f / D_MODEL) - mu * mu;
        st[(long long)b * 1024 + i] = make_float2(mu, rsqrtf(var + 1e-5f));
    }
}

// ================= LN2 transposed write =================
__global__ __launch_bounds__(256) void ln2_write(
    const float* __restrict__ F0, const float* __restrict__ F1,
    const __bf16* __restrict__ Hb, const float2* __restrict__ st,
    float* __restrict__ OUT)
{
    __shared__ float ts[32][33];
    int f0 = blockIdx.x * 32, i0 = blockIdx.y * 32, b = blockIdx.z;
    int tr = threadIdx.x >> 5, tc = threadIdx.x & 31;
    #pragma unroll
    for (int p = 0; p < 4; ++p) {
        int tok = i0 + tr + p * 8;
        long long tb = ((long long)b * 1024 + tok) * 1024;
        float2 s = st[(long long)b * 1024 + tok];
        float v = F0[tb + f0 + tc] + F1[tb + f0 + tc] + (float)Hb[tb + f0 + tc];
        ts[tr + p * 8][tc] = (v - s.x) * s.y;
    }
    __syncthreads();
    #pragma unroll
    for (int p = 0; p < 4; ++p)
        OUT[((long long)b * 1024 + f0 + tr + p * 8) * 1024 + i0 + tc] = ts[tc][tr + p * 8];
}

// ================= launch =================
extern "C" void kernel_launch(void* const* d_in, const int* in_sizes, int n_in,
                              void* d_out, int out_size, void* d_ws, size_t ws_size,
                              hipStream_t stream) {
    const float* z    = (const float*)d_in[0];
    const float* zh   = (const float*)d_in[1];
    const float* u    = (const float*)d_in[2];
    const float* pos  = (const float*)d_in[3];
    const float* Wqkv = (const float*)d_in[4];
    const float* Wr   = (const float*)d_in[5];
    const float* rwb  = (const float*)d_in[6];
    const float* rrb  = (const float*)d_in[7];
    const float* Wo   = (const float*)d_in[8];
    const float* bo   = (const float*)d_in[9];
    const float* Wff1 = (const float*)d_in[10];
    const float* bff1 = (const float*)d_in[11];
    const float* Wff2 = (const float*)d_in[12];
    const float* bff2 = (const float*)d_in[13];
    float* out = (float*)d_out;
    float* ws  = (float*)d_ws;

    __bf16* cat_t = (__bf16*)ws;
    __bf16* pos_t = (__bf16*)(ws + 2097152);
    __bf16* Wqkvb = (__bf16*)(ws + 3178496);
    __bf16* Wrb   = (__bf16*)(ws + 4751360);
    __bf16* Wob   = (__bf16*)(ws + 5275648);
    __bf16* Wff1b = (__bf16*)(ws + 5799936);
    __bf16* Wff2b = (__bf16*)(ws + 7897088);
    __bf16* qkT   = (__bf16*)(ws + 14188544);
    __bf16* wh_v  = (__bf16*)(ws + 18382848);
    __bf16* rkT   = (__bf16*)(ws + 20480000);
    __bf16* av_t  = (__bf16*)(ws + 21069824);
    float*  ao0   = ws + 22118400;
    float*  ao1   = ws + 24215552;
    __bf16* h_bf  = (__bf16*)(ws + 26312704);
    float2* st2   = (float2*)(ws + 27361280);
    __bf16* f1b   = (__bf16*)(ws + 14188544);
    float*  f20   = ws + 9994240;
    float*  f21   = ws + 12091392;

    prep_all<<<19520, 256, 0, stream>>>(
        Wqkv, Wqkvb, Wr, Wrb, Wo, Wob, Wff1, Wff1b, Wff2, Wff2b,
        zh, z, cat_t, pos, pos_t);

    gemm_fused3<<<840, 512, 0, stream>>>(
        cat_t, Wqkvb, qkT, u, wh_v, pos_t, Wrb, rkT);

    attn_mfma<<<256, 512, 0, stream>>>(qkT, wh_v, rkT, rwb, rrb, av_t);

    gemm_bf16_k<2><<<dim3(8, 32, 1), 512, 0, stream>>>(
        av_t, Wob, ao0, ao1, nullptr, nullptr, nullptr,
        1024, 1024, 1024, 1024, 0, 0);
    ln1_kernel<<<dim3(1024, 2), 256, 0, stream>>>(ao0, ao1, bo, cat_t, h_bf);
    gemm_bf16_k<1><<<dim3(32, 16, 1), 512, 0, stream>>>(
        h_bf, Wff1b, nullptr, nullptr, f1b, nullptr, bff1,
        1024, 1024, 1024, 4096, 0, 1);
    gemm_bf16_k<2><<<dim3(8, 32, 1), 512, 0, stream>>>(
        f1b, Wff2b, f20, f21, nullptr, nullptr, bff2,
        4096, 4096, 4096, 1024, 0, 0);
    ln2_stats<<<dim3(1024, 2), 256, 0, stream>>>(f20, f21, h_bf, st2);
    ln2_write<<<dim3(32, 32, 2), 256, 0, stream>>>(f20, f21, h_bf, st2, out);
}